// Round 1
// baseline (185.678 us; speedup 1.0000x reference)
//
#include <hip/hip_runtime.h>
#include <math.h>

// ---------------- problem constants ----------------
constexpr int NROWS = 131072;   // N
constexpr int DM    = 256;      // memory width
constexpr int HID   = 200;      // controller hidden
constexpr int ORD   = 262;      // read head out dim
constexpr int OWD   = 774;      // write head out dim
constexpr float EPSV = 1e-8f;

// d_out layout (floats): out[64] | M_new[N*256] | rw[N] | ww[N] | read[256]
constexpr long long OUT_OFF  = 0;
constexpr long long MNEW_OFF = 64;
constexpr long long RW_OFF   = 64LL + (long long)NROWS * DM;   // 33554496
constexpr long long WW_OFF   = RW_OFF + NROWS;                 // 33685568
constexpr long long READ_OFF = WW_OFF + NROWS;                 // 33816640

// scratch inside the (later fully overwritten) M_new region
constexpr long long U_R_OFF   = MNEW_OFF;                       // N floats
constexpr long long U_W_OFF   = MNEW_OFF + NROWS;               // N floats
constexpr long long PART_H_OFF  = MNEW_OFF + 2LL * NROWS;           // 16*200
constexpr long long PART_OR_OFF = MNEW_OFF + 2LL * NROWS + 4096;    // 25*262
constexpr long long PART_OW_OFF = MNEW_OFF + 2LL * NROWS + 16384;   // 25*774

// ws layout (floats) — only ~5.2 KB needed
constexpr int WS_H   = 0;     // h_final[200]
constexpr int WS_KNR = 256;   // kn_read[256]
constexpr int WS_KNW = 512;   // kn_write[256]
constexpr int WS_E   = 768;   // erase[256]
constexpr int WS_A   = 1024;  // add[256]
constexpr int WS_SC  = 1280;  // scalars[16]:
// 0 beta_r, 1 g_r, 2..4 s_r, 5 gamma_r, 6 beta_w, 7 g_w, 8..10 s_w, 11 gamma_w,
// 12 sum_r, 13 sum_w, 14 sumwp_r, 15 sumwp_w

__device__ __forceinline__ float softplusf(float x) {
    if (x > 20.0f) return x;
    return logf(1.0f + expf(x));
}
__device__ __forceinline__ float sigmoidf(float x) {
    return 1.0f / (1.0f + expf(-x));
}

// ---------------- K1: h partials: xc @ W1, 16 blocks x 32 rows ----------------
__global__ __launch_bounds__(256) void k1_hpart(
        const float* __restrict__ x, const float* __restrict__ read_prev,
        const float* __restrict__ reads_bias, const float* __restrict__ W1,
        float* __restrict__ part_h) {
    __shared__ float xc[512];
    int t = threadIdx.x;
    xc[t] = x[t];
    xc[256 + t] = read_prev[t] + reads_bias[t];
    __syncthreads();
    if (t < HID) {
        float acc = 0.f;
        int i0 = blockIdx.x * 32;
        #pragma unroll 8
        for (int r = 0; r < 32; ++r)
            acc += xc[i0 + r] * W1[(i0 + r) * HID + t];
        part_h[blockIdx.x * HID + t] = acc;
    }
}

// ---------------- K2: head GEMV partials: h @ {Wr, Ww}, 25 blocks x 8 rows ----
__global__ __launch_bounds__(256) void k2_heads(
        const float* __restrict__ part_h, const float* __restrict__ b1,
        const float* __restrict__ Wr, const float* __restrict__ Ww,
        float* __restrict__ part_or, float* __restrict__ part_ow) {
    __shared__ float h8[8];
    int t = threadIdx.x;
    if (t < 8) {
        int i = blockIdx.x * 8 + t;
        float v = b1[i];
        for (int b = 0; b < 16; ++b) v += part_h[b * HID + i];
        h8[t] = fmaxf(v, 0.f);
    }
    __syncthreads();
    float aor0 = 0.f, aor1 = 0.f, aow0 = 0.f, aow1 = 0.f, aow2 = 0.f, aow3 = 0.f;
    int i0 = blockIdx.x * 8;
    for (int r = 0; r < 8; ++r) {
        float hv = h8[r];
        const float* wr = Wr + (long long)(i0 + r) * ORD;
        const float* wwp = Ww + (long long)(i0 + r) * OWD;
        aor0 += hv * wr[t];
        if (t < 6) aor1 += hv * wr[256 + t];
        aow0 += hv * wwp[t];
        aow1 += hv * wwp[256 + t];
        aow2 += hv * wwp[512 + t];
        if (t < 6) aow3 += hv * wwp[768 + t];
    }
    part_or[blockIdx.x * ORD + t] = aor0;
    if (t < 6) part_or[blockIdx.x * ORD + 256 + t] = aor1;
    float* po = part_ow + blockIdx.x * OWD;
    po[t] = aow0;
    po[256 + t] = aow1;
    po[512 + t] = aow2;
    if (t < 6) po[768 + t] = aow3;
}

// ---------------- K3: finalize heads -> params in ws; zero accumulators ------
__global__ __launch_bounds__(256) void k3_params(
        const float* __restrict__ part_h, const float* __restrict__ b1,
        const float* __restrict__ part_or, const float* __restrict__ br,
        const float* __restrict__ part_ow, const float* __restrict__ bw,
        float* ws, float* __restrict__ read_out) {
    __shared__ float orh[ORD];
    __shared__ float owh[OWD];
    __shared__ float rbuf[8];
    int t = threadIdx.x;
    for (int j = t; j < ORD; j += 256) {
        float v = br[j];
        for (int b = 0; b < 25; ++b) v += part_or[b * ORD + j];
        orh[j] = v;
    }
    for (int j = t; j < OWD; j += 256) {
        float v = bw[j];
        for (int b = 0; b < 25; ++b) v += part_ow[b * OWD + j];
        owh[j] = v;
    }
    if (t < HID) {
        float v = b1[t];
        for (int b = 0; b < 16; ++b) v += part_h[b * HID + t];
        ws[WS_H + t] = fmaxf(v, 0.f);
    }
    read_out[t] = 0.f;                 // zero read accumulator (d_out region)
    if (t < 4) ws[WS_SC + 12 + t] = 0.f;  // zero sum_r, sum_w, sumwp_r, sumwp_w
    __syncthreads();

    float kr = tanhf(orh[t]);
    float kw = tanhf(owh[t]);
    float nr = kr * kr, nw = kw * kw;
    #pragma unroll
    for (int s = 32; s > 0; s >>= 1) {
        nr += __shfl_xor(nr, s, 64);
        nw += __shfl_xor(nw, s, 64);
    }
    int wid = t >> 6, lane = t & 63;
    if (lane == 0) { rbuf[wid] = nr; rbuf[4 + wid] = nw; }
    __syncthreads();
    float normr = sqrtf(rbuf[0] + rbuf[1] + rbuf[2] + rbuf[3]) + EPSV;
    float normw = sqrtf(rbuf[4] + rbuf[5] + rbuf[6] + rbuf[7]) + EPSV;
    ws[WS_KNR + t] = kr / normr;
    ws[WS_KNW + t] = kw / normw;
    ws[WS_E + t] = sigmoidf(owh[262 + t]);
    ws[WS_A + t] = tanhf(owh[518 + t]);
    if (t == 0) {
        ws[WS_SC + 0] = softplusf(orh[256]);
        ws[WS_SC + 1] = sigmoidf(orh[257]);
        float m3 = fmaxf(orh[258], fmaxf(orh[259], orh[260]));
        float e0 = expf(orh[258] - m3), e1 = expf(orh[259] - m3), e2 = expf(orh[260] - m3);
        float es = e0 + e1 + e2;
        ws[WS_SC + 2] = e0 / es; ws[WS_SC + 3] = e1 / es; ws[WS_SC + 4] = e2 / es;
        ws[WS_SC + 5] = 1.0f + softplusf(orh[261]);
        ws[WS_SC + 6] = softplusf(owh[256]);
        ws[WS_SC + 7] = sigmoidf(owh[257]);
        float m3w = fmaxf(owh[258], fmaxf(owh[259], owh[260]));
        float f0 = expf(owh[258] - m3w), f1 = expf(owh[259] - m3w), f2 = expf(owh[260] - m3w);
        float fs = f0 + f1 + f2;
        ws[WS_SC + 8] = f0 / fs; ws[WS_SC + 9] = f1 / fs; ws[WS_SC + 10] = f2 / fs;
        ws[WS_SC + 11] = 1.0f + softplusf(owh[261]);
    }
}

// ---------------- K4: M pass 1 — content scores -> u, sums -------------------
__global__ __launch_bounds__(256) void k4_scores(
        const float* __restrict__ M, float* ws,
        float* __restrict__ u_r, float* __restrict__ u_w) {
    __shared__ float sbuf[8];
    int t = threadIdx.x;
    int lane = t & 63, wid = t >> 6;
    const float4 knr = *(const float4*)(ws + WS_KNR + lane * 4);
    const float4 knw = *(const float4*)(ws + WS_KNW + lane * 4);
    float beta_r = ws[WS_SC + 0], beta_w = ws[WS_SC + 6];
    int n0 = (blockIdx.x * 4 + wid) * 32;
    float sr = 0.f, sw = 0.f;
    for (int r = 0; r < 32; ++r) {
        int n = n0 + r;
        const float4 m = *(const float4*)(M + (long long)n * DM + lane * 4);
        float nn = m.x * m.x + m.y * m.y + m.z * m.z + m.w * m.w;
        float dr = m.x * knr.x + m.y * knr.y + m.z * knr.z + m.w * knr.w;
        float dw = m.x * knw.x + m.y * knw.y + m.z * knw.z + m.w * knw.w;
        #pragma unroll
        for (int s = 32; s > 0; s >>= 1) {
            nn += __shfl_xor(nn, s, 64);
            dr += __shfl_xor(dr, s, 64);
            dw += __shfl_xor(dw, s, 64);
        }
        float rn = 1.0f / (sqrtf(nn) + EPSV);
        // exp(beta*(cos-1)) == exp(score - beta): exact softmax shift, cos<=1
        float ur = expf(beta_r * (dr * rn - 1.0f));
        float uw = expf(beta_w * (dw * rn - 1.0f));
        if (lane == 0) { u_r[n] = ur; u_w[n] = uw; }
        sr += ur; sw += uw;
    }
    if (lane == 0) { sbuf[wid] = sr; sbuf[4 + wid] = sw; }
    __syncthreads();
    if (t == 0) {
        atomicAdd(&ws[WS_SC + 12], sbuf[0] + sbuf[1] + sbuf[2] + sbuf[3]);
        atomicAdd(&ws[WS_SC + 13], sbuf[4] + sbuf[5] + sbuf[6] + sbuf[7]);
    }
}

// ---------------- K5: gate + circular shift + pow + sum ----------------------
__global__ __launch_bounds__(256) void k5_shift(
        const float* __restrict__ u_r, const float* __restrict__ u_w,
        const float* __restrict__ read_w, const float* __restrict__ write_w,
        float* ws, float* __restrict__ wp_r, float* __restrict__ wp_w) {
    __shared__ float sbuf[8];
    int tid = blockIdx.x * 256 + threadIdx.x;
    float g_r = ws[WS_SC + 1], g_w = ws[WS_SC + 7];
    float omg_r = 1.f - g_r, omg_w = 1.f - g_w;
    float sr0 = ws[WS_SC + 2], sr1 = ws[WS_SC + 3], sr2 = ws[WS_SC + 4];
    float sw0 = ws[WS_SC + 8], sw1 = ws[WS_SC + 9], sw2 = ws[WS_SC + 10];
    float gam_r = ws[WS_SC + 5], gam_w = ws[WS_SC + 11];
    float isr = g_r / ws[WS_SC + 12];   // fold gate into softmax scale
    float isw = g_w / ws[WS_SC + 13];
    float lr = 0.f, lw = 0.f;
    for (int n = tid; n < NROWS; n += gridDim.x * 256) {
        int nm = (n == 0) ? NROWS - 1 : n - 1;
        int np = (n == NROWS - 1) ? 0 : n + 1;
        float wgm = u_r[nm] * isr + omg_r * read_w[nm];
        float wg0 = u_r[n]  * isr + omg_r * read_w[n];
        float wgp = u_r[np] * isr + omg_r * read_w[np];
        float wt = sr0 * wgp + sr1 * wg0 + sr2 * wgm;
        float wp = powf(wt, gam_r);
        wp_r[n] = wp; lr += wp;
        float vgm = u_w[nm] * isw + omg_w * write_w[nm];
        float vg0 = u_w[n]  * isw + omg_w * write_w[n];
        float vgp = u_w[np] * isw + omg_w * write_w[np];
        float vt = sw0 * vgp + sw1 * vg0 + sw2 * vgm;
        float vp = powf(vt, gam_w);
        wp_w[n] = vp; lw += vp;
    }
    #pragma unroll
    for (int s = 32; s > 0; s >>= 1) {
        lr += __shfl_xor(lr, s, 64);
        lw += __shfl_xor(lw, s, 64);
    }
    int wid = threadIdx.x >> 6, lane = threadIdx.x & 63;
    if (lane == 0) { sbuf[wid] = lr; sbuf[4 + wid] = lw; }
    __syncthreads();
    if (threadIdx.x == 0) {
        atomicAdd(&ws[WS_SC + 14], sbuf[0] + sbuf[1] + sbuf[2] + sbuf[3]);
        atomicAdd(&ws[WS_SC + 15], sbuf[4] + sbuf[5] + sbuf[6] + sbuf[7]);
    }
}

// ---------------- K6: M pass 2 — rw/ww finalize, M_new, read partials --------
__global__ __launch_bounds__(256) void k6_update(
        const float* __restrict__ M, float* ws, float* dout) {
    __shared__ float lds[4][256];
    int t = threadIdx.x;
    int lane = t & 63, wid = t >> 6;
    const float4 e4 = *(const float4*)(ws + WS_E + lane * 4);
    const float4 a4 = *(const float4*)(ws + WS_A + lane * 4);
    float inv_r = 1.0f / (ws[WS_SC + 14] + EPSV);
    float inv_w = 1.0f / (ws[WS_SC + 15] + EPSV);
    float* rw = dout + RW_OFF;   // currently holds wp_r
    float* wwv_buf = dout + WW_OFF;  // currently holds wp_w
    float* mn = dout + MNEW_OFF;
    int n0 = (blockIdx.x * 4 + wid) * 32;
    float4 acc = {0.f, 0.f, 0.f, 0.f};
    for (int r = 0; r < 32; ++r) {
        int n = n0 + r;
        float rwv = rw[n] * inv_r;
        float wwv = wwv_buf[n] * inv_w;
        const float4 m = *(const float4*)(M + (long long)n * DM + lane * 4);
        acc.x += rwv * m.x; acc.y += rwv * m.y;
        acc.z += rwv * m.z; acc.w += rwv * m.w;
        float4 o;
        o.x = m.x * (1.0f - wwv * e4.x) + wwv * a4.x;
        o.y = m.y * (1.0f - wwv * e4.y) + wwv * a4.y;
        o.z = m.z * (1.0f - wwv * e4.z) + wwv * a4.z;
        o.w = m.w * (1.0f - wwv * e4.w) + wwv * a4.w;
        *(float4*)(mn + (long long)n * DM + lane * 4) = o;
        if (lane == 0) { rw[n] = rwv; wwv_buf[n] = wwv; }
    }
    *(float4*)(&lds[wid][lane * 4]) = acc;
    __syncthreads();
    float s = lds[0][t] + lds[1][t] + lds[2][t] + lds[3][t];
    atomicAdd(&dout[READ_OFF + t], s);
}

// ---------------- K7: output MLP epilogue ------------------------------------
__global__ __launch_bounds__(256) void k7_out(
        const float* ws, const float* __restrict__ Wo1, const float* __restrict__ bo1,
        const float* __restrict__ Wo2, const float* __restrict__ bo2, float* dout) {
    __shared__ float c[456];
    __shared__ float h2[100];
    int t = threadIdx.x;
    if (t < HID) c[t] = ws[WS_H + t];
    c[200 + t] = dout[READ_OFF + t];
    __syncthreads();
    if (t < 100) {
        float acc = bo1[t];
        #pragma unroll 8
        for (int i = 0; i < 456; ++i) acc += c[i] * Wo1[i * 100 + t];
        h2[t] = fmaxf(acc, 0.f);
    }
    __syncthreads();
    if (t < 64) {
        float acc = bo2[t];
        #pragma unroll
        for (int i = 0; i < 100; ++i) acc += h2[i] * Wo2[i * 64 + t];
        dout[t] = acc;
    }
}

extern "C" void kernel_launch(void* const* d_in, const int* in_sizes, int n_in,
                              void* d_out, int out_size, void* d_ws, size_t ws_size,
                              hipStream_t stream) {
    const float* x          = (const float*)d_in[0];
    const float* M          = (const float*)d_in[1];
    const float* read_w     = (const float*)d_in[2];
    const float* write_w    = (const float*)d_in[3];
    const float* read_prev  = (const float*)d_in[4];
    const float* reads_bias = (const float*)d_in[5];
    const float* W1  = (const float*)d_in[6];
    const float* b1  = (const float*)d_in[7];
    const float* Wr  = (const float*)d_in[8];
    const float* br  = (const float*)d_in[9];
    const float* Ww  = (const float*)d_in[10];
    const float* bw  = (const float*)d_in[11];
    const float* Wo1 = (const float*)d_in[12];
    const float* bo1 = (const float*)d_in[13];
    const float* Wo2 = (const float*)d_in[14];
    const float* bo2 = (const float*)d_in[15];
    float* dout = (float*)d_out;
    float* ws   = (float*)d_ws;

    float* part_h  = dout + PART_H_OFF;
    float* part_or = dout + PART_OR_OFF;
    float* part_ow = dout + PART_OW_OFF;
    float* u_r = dout + U_R_OFF;
    float* u_w = dout + U_W_OFF;

    k1_hpart<<<16, 256, 0, stream>>>(x, read_prev, reads_bias, W1, part_h);
    k2_heads<<<25, 256, 0, stream>>>(part_h, b1, Wr, Ww, part_or, part_ow);
    k3_params<<<1, 256, 0, stream>>>(part_h, b1, part_or, br, part_ow, bw,
                                     ws, dout + READ_OFF);
    k4_scores<<<1024, 256, 0, stream>>>(M, ws, u_r, u_w);
    k5_shift<<<512, 256, 0, stream>>>(u_r, u_w, read_w, write_w, ws,
                                      dout + RW_OFF, dout + WW_OFF);
    k6_update<<<1024, 256, 0, stream>>>(M, ws, dout);
    k7_out<<<1, 256, 0, stream>>>(ws, Wo1, bo1, Wo2, bo2, dout);
}

// Round 3
// 162.077 us; speedup vs baseline: 1.1456x; 1.1456x over previous
//
#include <hip/hip_runtime.h>
#include <math.h>

typedef float f32x4 __attribute__((ext_vector_type(4)));

// ---------------- problem constants ----------------
constexpr int NROWS = 131072;   // N
constexpr int DM    = 256;      // memory width
constexpr int HID   = 200;      // controller hidden
constexpr int ORD   = 262;      // read head out dim
constexpr int OWD   = 774;      // write head out dim
constexpr float EPSV = 1e-8f;

// d_out layout (floats): out[64] | M_new[N*256] | rw[N] | ww[N] | read[256]
constexpr long long OUT_OFF  = 0;
constexpr long long MNEW_OFF = 64;
constexpr long long RW_OFF   = 64LL + (long long)NROWS * DM;
constexpr long long WW_OFF   = RW_OFF + NROWS;
constexpr long long READ_OFF = WW_OFF + NROWS;

// scratch inside the (later fully overwritten) M_new region
constexpr long long U_R_OFF   = MNEW_OFF;                       // N floats
constexpr long long U_W_OFF   = MNEW_OFF + NROWS;               // N floats
constexpr long long PART_H_OFF  = MNEW_OFF + 2LL * NROWS;           // 16*200
constexpr long long PART_OR_OFF = MNEW_OFF + 2LL * NROWS + 4096;    // 25*262
constexpr long long PART_OW_OFF = MNEW_OFF + 2LL * NROWS + 16384;   // 25*774

// ws layout (floats)
constexpr int WS_H   = 0;     // h_final[200]
constexpr int WS_KNR = 256;   // kn_read[256]
constexpr int WS_KNW = 512;   // kn_write[256]
constexpr int WS_E   = 768;   // erase[256]
constexpr int WS_A   = 1024;  // add[256]
constexpr int WS_SC  = 1280;  // scalars[16]:
// 0 beta_r, 1 g_r, 2..4 s_r, 5 gamma_r, 6 beta_w, 7 g_w, 8..10 s_w, 11 gamma_w,
// 12 sum_r, 13 sum_w, 14 sumwp_r, 15 sumwp_w

__device__ __forceinline__ float softplusf(float x) {
    if (x > 20.0f) return x;
    return logf(1.0f + expf(x));
}
__device__ __forceinline__ float sigmoidf(float x) {
    return 1.0f / (1.0f + expf(-x));
}

// ---------------- K1: h partials: xc @ W1, 16 blocks x 32 rows ----------------
__global__ __launch_bounds__(256) void k1_hpart(
        const float* __restrict__ x, const float* __restrict__ read_prev,
        const float* __restrict__ reads_bias, const float* __restrict__ W1,
        float* __restrict__ part_h) {
    __shared__ float xc[512];
    int t = threadIdx.x;
    xc[t] = x[t];
    xc[256 + t] = read_prev[t] + reads_bias[t];
    __syncthreads();
    if (t < HID) {
        float acc = 0.f;
        int i0 = blockIdx.x * 32;
        #pragma unroll 8
        for (int r = 0; r < 32; ++r)
            acc += xc[i0 + r] * W1[(i0 + r) * HID + t];
        part_h[blockIdx.x * HID + t] = acc;
    }
}

// ---------------- K2: head GEMV partials: h @ {Wr, Ww}, 25 blocks x 8 rows ----
__global__ __launch_bounds__(256) void k2_heads(
        const float* __restrict__ part_h, const float* __restrict__ b1,
        const float* __restrict__ Wr, const float* __restrict__ Ww,
        float* __restrict__ part_or, float* __restrict__ part_ow) {
    __shared__ float h8[8];
    int t = threadIdx.x;
    if (t < 8) {
        int i = blockIdx.x * 8 + t;
        float v = b1[i];
        for (int b = 0; b < 16; ++b) v += part_h[b * HID + i];
        h8[t] = fmaxf(v, 0.f);
    }
    __syncthreads();
    float aor0 = 0.f, aor1 = 0.f, aow0 = 0.f, aow1 = 0.f, aow2 = 0.f, aow3 = 0.f;
    int i0 = blockIdx.x * 8;
    for (int r = 0; r < 8; ++r) {
        float hv = h8[r];
        const float* wr = Wr + (long long)(i0 + r) * ORD;
        const float* wwp = Ww + (long long)(i0 + r) * OWD;
        aor0 += hv * wr[t];
        if (t < 6) aor1 += hv * wr[256 + t];
        aow0 += hv * wwp[t];
        aow1 += hv * wwp[256 + t];
        aow2 += hv * wwp[512 + t];
        if (t < 6) aow3 += hv * wwp[768 + t];
    }
    part_or[blockIdx.x * ORD + t] = aor0;
    if (t < 6) part_or[blockIdx.x * ORD + 256 + t] = aor1;
    float* po = part_ow + blockIdx.x * OWD;
    po[t] = aow0;
    po[256 + t] = aow1;
    po[512 + t] = aow2;
    if (t < 6) po[768 + t] = aow3;
}

// ---------------- K3: finalize heads -> params in ws; zero accumulators ------
__global__ __launch_bounds__(256) void k3_params(
        const float* __restrict__ part_h, const float* __restrict__ b1,
        const float* __restrict__ part_or, const float* __restrict__ br,
        const float* __restrict__ part_ow, const float* __restrict__ bw,
        float* ws, float* __restrict__ read_out) {
    __shared__ float orh[ORD];
    __shared__ float owh[OWD];
    __shared__ float rbuf[8];
    int t = threadIdx.x;
    for (int j = t; j < ORD; j += 256) {
        float v = br[j];
        for (int b = 0; b < 25; ++b) v += part_or[b * ORD + j];
        orh[j] = v;
    }
    for (int j = t; j < OWD; j += 256) {
        float v = bw[j];
        for (int b = 0; b < 25; ++b) v += part_ow[b * OWD + j];
        owh[j] = v;
    }
    if (t < HID) {
        float v = b1[t];
        for (int b = 0; b < 16; ++b) v += part_h[b * HID + t];
        ws[WS_H + t] = fmaxf(v, 0.f);
    }
    read_out[t] = 0.f;                 // zero read accumulator (d_out region)
    if (t < 4) ws[WS_SC + 12 + t] = 0.f;  // zero sum_r, sum_w, sumwp_r, sumwp_w
    __syncthreads();

    float kr = tanhf(orh[t]);
    float kw = tanhf(owh[t]);
    float nr = kr * kr, nw = kw * kw;
    #pragma unroll
    for (int s = 32; s > 0; s >>= 1) {
        nr += __shfl_xor(nr, s, 64);
        nw += __shfl_xor(nw, s, 64);
    }
    int wid = t >> 6, lane = t & 63;
    if (lane == 0) { rbuf[wid] = nr; rbuf[4 + wid] = nw; }
    __syncthreads();
    float normr = sqrtf(rbuf[0] + rbuf[1] + rbuf[2] + rbuf[3]) + EPSV;
    float normw = sqrtf(rbuf[4] + rbuf[5] + rbuf[6] + rbuf[7]) + EPSV;
    ws[WS_KNR + t] = kr / normr;
    ws[WS_KNW + t] = kw / normw;
    ws[WS_E + t] = sigmoidf(owh[262 + t]);
    ws[WS_A + t] = tanhf(owh[518 + t]);
    if (t == 0) {
        ws[WS_SC + 0] = softplusf(orh[256]);
        ws[WS_SC + 1] = sigmoidf(orh[257]);
        float m3 = fmaxf(orh[258], fmaxf(orh[259], orh[260]));
        float e0 = expf(orh[258] - m3), e1 = expf(orh[259] - m3), e2 = expf(orh[260] - m3);
        float es = e0 + e1 + e2;
        ws[WS_SC + 2] = e0 / es; ws[WS_SC + 3] = e1 / es; ws[WS_SC + 4] = e2 / es;
        ws[WS_SC + 5] = 1.0f + softplusf(orh[261]);
        ws[WS_SC + 6] = softplusf(owh[256]);
        ws[WS_SC + 7] = sigmoidf(owh[257]);
        float m3w = fmaxf(owh[258], fmaxf(owh[259], owh[260]));
        float f0 = expf(owh[258] - m3w), f1 = expf(owh[259] - m3w), f2 = expf(owh[260] - m3w);
        float fs = f0 + f1 + f2;
        ws[WS_SC + 8] = f0 / fs; ws[WS_SC + 9] = f1 / fs; ws[WS_SC + 10] = f2 / fs;
        ws[WS_SC + 11] = 1.0f + softplusf(owh[261]);
    }
}

// ---------------- K4: M pass 1 — content scores -> u, sums -------------------
// 1024 blocks x 4 waves; 32 rows per wave, processed 2 rows/iter for ILP.
__global__ __launch_bounds__(256) void k4_scores(
        const float* __restrict__ M, float* ws,
        float* __restrict__ u_r, float* __restrict__ u_w) {
    __shared__ float sbuf[8];
    int t = threadIdx.x, lane = t & 63, wid = t >> 6;
    const f32x4 knr = *(const f32x4*)(ws + WS_KNR + lane * 4);
    const f32x4 knw = *(const f32x4*)(ws + WS_KNW + lane * 4);
    float beta_r = ws[WS_SC + 0], beta_w = ws[WS_SC + 6];
    int n0 = blockIdx.x * 128 + wid * 32;
    const float* mb = M + (long long)n0 * DM + lane * 4;
    float sr = 0.f, sw = 0.f;
    float uval = 0.f;  // lane r<32 -> u_r[row r]; lane 32+r -> u_w[row r]
    #pragma unroll 4
    for (int r = 0; r < 32; r += 2) {
        const f32x4 a0 = *(const f32x4*)(mb + (long long)r * DM);
        const f32x4 a1 = *(const f32x4*)(mb + (long long)(r + 1) * DM);
        float nn0 = a0.x*a0.x + a0.y*a0.y + a0.z*a0.z + a0.w*a0.w;
        float dr0 = a0.x*knr.x + a0.y*knr.y + a0.z*knr.z + a0.w*knr.w;
        float dw0 = a0.x*knw.x + a0.y*knw.y + a0.z*knw.z + a0.w*knw.w;
        float nn1 = a1.x*a1.x + a1.y*a1.y + a1.z*a1.z + a1.w*a1.w;
        float dr1 = a1.x*knr.x + a1.y*knr.y + a1.z*knr.z + a1.w*knr.w;
        float dw1 = a1.x*knw.x + a1.y*knw.y + a1.z*knw.z + a1.w*knw.w;
        #pragma unroll
        for (int s = 32; s > 0; s >>= 1) {
            nn0 += __shfl_xor(nn0, s, 64);
            dr0 += __shfl_xor(dr0, s, 64);
            dw0 += __shfl_xor(dw0, s, 64);
            nn1 += __shfl_xor(nn1, s, 64);
            dr1 += __shfl_xor(dr1, s, 64);
            dw1 += __shfl_xor(dw1, s, 64);
        }
        float rn0 = 1.0f / (sqrtf(nn0) + EPSV);
        float rn1 = 1.0f / (sqrtf(nn1) + EPSV);
        // exp(beta*(cos-1)) == stabilized softmax numerator (cos <= 1)
        float ur0 = expf(beta_r * (dr0 * rn0 - 1.0f));
        float uw0 = expf(beta_w * (dw0 * rn0 - 1.0f));
        float ur1 = expf(beta_r * (dr1 * rn1 - 1.0f));
        float uw1 = expf(beta_w * (dw1 * rn1 - 1.0f));
        sr += ur0 + ur1; sw += uw0 + uw1;
        if (lane == r)          uval = ur0;
        if (lane == r + 1)      uval = ur1;
        if (lane == 32 + r)     uval = uw0;
        if (lane == 32 + r + 1) uval = uw1;
    }
    if (lane < 32) u_r[n0 + lane] = uval;
    else           u_w[n0 + lane - 32] = uval;
    if (lane == 0) { sbuf[wid] = sr; sbuf[4 + wid] = sw; }
    __syncthreads();
    if (t == 0) {
        atomicAdd(&ws[WS_SC + 12], sbuf[0] + sbuf[1] + sbuf[2] + sbuf[3]);
        atomicAdd(&ws[WS_SC + 13], sbuf[4] + sbuf[5] + sbuf[6] + sbuf[7]);
    }
}

// ---------------- K5: gate + circular shift + pow + sum ----------------------
__global__ __launch_bounds__(256) void k5_shift(
        const float* __restrict__ u_r, const float* __restrict__ u_w,
        const float* __restrict__ read_w, const float* __restrict__ write_w,
        float* ws, float* __restrict__ wp_r, float* __restrict__ wp_w) {
    __shared__ float sbuf[8];
    int tid = blockIdx.x * 256 + threadIdx.x;
    float g_r = ws[WS_SC + 1], g_w = ws[WS_SC + 7];
    float omg_r = 1.f - g_r, omg_w = 1.f - g_w;
    float sr0 = ws[WS_SC + 2], sr1 = ws[WS_SC + 3], sr2 = ws[WS_SC + 4];
    float sw0 = ws[WS_SC + 8], sw1 = ws[WS_SC + 9], sw2 = ws[WS_SC + 10];
    float gam_r = ws[WS_SC + 5], gam_w = ws[WS_SC + 11];
    float isr = g_r / ws[WS_SC + 12];   // fold gate into softmax scale
    float isw = g_w / ws[WS_SC + 13];
    float lr = 0.f, lw = 0.f;
    for (int n = tid; n < NROWS; n += gridDim.x * 256) {
        int nm = (n == 0) ? NROWS - 1 : n - 1;
        int np = (n == NROWS - 1) ? 0 : n + 1;
        float wgm = u_r[nm] * isr + omg_r * read_w[nm];
        float wg0 = u_r[n]  * isr + omg_r * read_w[n];
        float wgp = u_r[np] * isr + omg_r * read_w[np];
        float wt = sr0 * wgp + sr1 * wg0 + sr2 * wgm;
        float wp = powf(wt, gam_r);
        wp_r[n] = wp; lr += wp;
        float vgm = u_w[nm] * isw + omg_w * write_w[nm];
        float vg0 = u_w[n]  * isw + omg_w * write_w[n];
        float vgp = u_w[np] * isw + omg_w * write_w[np];
        float vt = sw0 * vgp + sw1 * vg0 + sw2 * vgm;
        float vp = powf(vt, gam_w);
        wp_w[n] = vp; lw += vp;
    }
    #pragma unroll
    for (int s = 32; s > 0; s >>= 1) {
        lr += __shfl_xor(lr, s, 64);
        lw += __shfl_xor(lw, s, 64);
    }
    int wid = threadIdx.x >> 6, lane = threadIdx.x & 63;
    if (lane == 0) { sbuf[wid] = lr; sbuf[4 + wid] = lw; }
    __syncthreads();
    if (threadIdx.x == 0) {
        atomicAdd(&ws[WS_SC + 14], sbuf[0] + sbuf[1] + sbuf[2] + sbuf[3]);
        atomicAdd(&ws[WS_SC + 15], sbuf[4] + sbuf[5] + sbuf[6] + sbuf[7]);
    }
}

// ---------------- K6: M pass 2 — rw/ww finalize, M_new (nt), read partials ---
// 1024 blocks x 4 waves; 32 rows per wave. wp via one vector load + shfl bcast.
__global__ __launch_bounds__(256) void k6_update(
        const float* __restrict__ M, float* ws, float* dout) {
    __shared__ float lds[4][256];
    int t = threadIdx.x, lane = t & 63, wid = t >> 6;
    const f32x4 e4 = *(const f32x4*)(ws + WS_E + lane * 4);
    const f32x4 a4 = *(const f32x4*)(ws + WS_A + lane * 4);
    float inv_r = 1.0f / (ws[WS_SC + 14] + EPSV);
    float inv_w = 1.0f / (ws[WS_SC + 15] + EPSV);
    float* rw = dout + RW_OFF;       // holds wp_r on entry
    float* wwb = dout + WW_OFF;      // holds wp_w on entry
    float* mn = dout + MNEW_OFF;
    int n0 = blockIdx.x * 128 + wid * 32;
    // lane r<32 holds wp_r[n0+r]; lane 32+r holds wp_w[n0+r]
    float wpv = (lane < 32) ? rw[n0 + lane] : wwb[n0 + lane - 32];
    const float* mb = M + (long long)n0 * DM + lane * 4;
    float* ob = mn + (long long)n0 * DM + lane * 4;
    f32x4 acc = {0.f, 0.f, 0.f, 0.f};
    #pragma unroll 8
    for (int r = 0; r < 32; ++r) {
        float rwv = __shfl(wpv, r, 64) * inv_r;
        float wwv = __shfl(wpv, 32 + r, 64) * inv_w;
        const f32x4 m = *(const f32x4*)(mb + (long long)r * DM);
        f32x4 o;
        acc.x += rwv * m.x; acc.y += rwv * m.y;
        acc.z += rwv * m.z; acc.w += rwv * m.w;
        o.x = m.x * (1.0f - wwv * e4.x) + wwv * a4.x;
        o.y = m.y * (1.0f - wwv * e4.y) + wwv * a4.y;
        o.z = m.z * (1.0f - wwv * e4.z) + wwv * a4.z;
        o.w = m.w * (1.0f - wwv * e4.w) + wwv * a4.w;
        __builtin_nontemporal_store(o, (f32x4*)(ob + (long long)r * DM));
    }
    // write normalized weights back (coalesced, after all reads)
    if (lane < 32) rw[n0 + lane] = wpv * inv_r;
    else           wwb[n0 + lane - 32] = wpv * inv_w;
    *(f32x4*)(&lds[wid][lane * 4]) = acc;
    __syncthreads();
    float s = lds[0][t] + lds[1][t] + lds[2][t] + lds[3][t];
    atomicAdd(&dout[READ_OFF + t], s);
}

// ---------------- K7: output MLP epilogue ------------------------------------
__global__ __launch_bounds__(256) void k7_out(
        const float* ws, const float* __restrict__ Wo1, const float* __restrict__ bo1,
        const float* __restrict__ Wo2, const float* __restrict__ bo2, float* dout) {
    __shared__ float c[456];
    __shared__ float h2[100];
    int t = threadIdx.x;
    if (t < HID) c[t] = ws[WS_H + t];
    c[200 + t] = dout[READ_OFF + t];
    __syncthreads();
    if (t < 100) {
        float acc = bo1[t];
        #pragma unroll 8
        for (int i = 0; i < 456; ++i) acc += c[i] * Wo1[i * 100 + t];
        h2[t] = fmaxf(acc, 0.f);
    }
    __syncthreads();
    if (t < 64) {
        float acc = bo2[t];
        #pragma unroll
        for (int i = 0; i < 100; ++i) acc += h2[i] * Wo2[i * 64 + t];
        dout[t] = acc;
    }
}

extern "C" void kernel_launch(void* const* d_in, const int* in_sizes, int n_in,
                              void* d_out, int out_size, void* d_ws, size_t ws_size,
                              hipStream_t stream) {
    const float* x          = (const float*)d_in[0];
    const float* M          = (const float*)d_in[1];
    const float* read_w     = (const float*)d_in[2];
    const float* write_w    = (const float*)d_in[3];
    const float* read_prev  = (const float*)d_in[4];
    const float* reads_bias = (const float*)d_in[5];
    const float* W1  = (const float*)d_in[6];
    const float* b1  = (const float*)d_in[7];
    const float* Wr  = (const float*)d_in[8];
    const float* br  = (const float*)d_in[9];
    const float* Ww  = (const float*)d_in[10];
    const float* bw  = (const float*)d_in[11];
    const float* Wo1 = (const float*)d_in[12];
    const float* bo1 = (const float*)d_in[13];
    const float* Wo2 = (const float*)d_in[14];
    const float* bo2 = (const float*)d_in[15];
    float* dout = (float*)d_out;
    float* ws   = (float*)d_ws;

    float* part_h  = dout + PART_H_OFF;
    float* part_or = dout + PART_OR_OFF;
    float* part_ow = dout + PART_OW_OFF;
    float* u_r = dout + U_R_OFF;
    float* u_w = dout + U_W_OFF;

    k1_hpart<<<16, 256, 0, stream>>>(x, read_prev, reads_bias, W1, part_h);
    k2_heads<<<25, 256, 0, stream>>>(part_h, b1, Wr, Ww, part_or, part_ow);
    k3_params<<<1, 256, 0, stream>>>(part_h, b1, part_or, br, part_ow, bw,
                                     ws, dout + READ_OFF);
    k4_scores<<<1024, 256, 0, stream>>>(M, ws, u_r, u_w);
    k5_shift<<<512, 256, 0, stream>>>(u_r, u_w, read_w, write_w, ws,
                                      dout + RW_OFF, dout + WW_OFF);
    k6_update<<<1024, 256, 0, stream>>>(M, ws, dout);
    k7_out<<<1, 256, 0, stream>>>(ws, Wo1, bo1, Wo2, bo2, dout);
}

// Round 4
// 149.317 us; speedup vs baseline: 1.2435x; 1.0855x over previous
//
#include <hip/hip_runtime.h>
#include <math.h>

typedef float f32x4 __attribute__((ext_vector_type(4)));

// ---------------- problem constants ----------------
constexpr int NROWS = 131072;   // N
constexpr int DM    = 256;      // memory width
constexpr int HID   = 200;      // controller hidden
constexpr int ORD   = 262;      // read head out dim
constexpr int OWD   = 774;      // write head out dim
constexpr float EPSV = 1e-8f;

// d_out layout (floats): out[64] | M_new[N*256] | rw[N] | ww[N] | read[256]
constexpr long long OUT_OFF  = 0;
constexpr long long MNEW_OFF = 64;
constexpr long long RW_OFF   = 64LL + (long long)NROWS * DM;
constexpr long long WW_OFF   = RW_OFF + NROWS;
constexpr long long READ_OFF = WW_OFF + NROWS;

// scratch inside the (later fully overwritten) M_new region
constexpr long long U_R_OFF   = MNEW_OFF;                       // N floats
constexpr long long U_W_OFF   = MNEW_OFF + NROWS;               // N floats
constexpr long long PART_H_OFF  = MNEW_OFF + 2LL * NROWS;           // 16*200
constexpr long long PART_OR_OFF = MNEW_OFF + 2LL * NROWS + 4096;    // 25*262
constexpr long long PART_OW_OFF = MNEW_OFF + 2LL * NROWS + 16384;   // 25*774

// ws layout (floats)
constexpr int WS_H   = 0;     // h_final[200]
constexpr int WS_KNR = 256;   // kn_read[256]
constexpr int WS_KNW = 512;   // kn_write[256]
constexpr int WS_E   = 768;   // erase[256]
constexpr int WS_A   = 1024;  // add[256]
constexpr int WS_SC  = 1280;  // scalars[16]:
// 0 beta_r, 1 g_r, 2..4 s_r, 5 gamma_r, 6 beta_w, 7 g_w, 8..10 s_w, 11 gamma_w,
// 12 sum_r, 13 sum_w, 14 sumwp_r, 15 sumwp_w

__device__ __forceinline__ float softplusf(float x) {
    if (x > 20.0f) return x;
    return logf(1.0f + expf(x));
}
__device__ __forceinline__ float sigmoidf(float x) {
    return 1.0f / (1.0f + expf(-x));
}
__device__ __forceinline__ float dot4(f32x4 a, f32x4 b) {
    return a.x * b.x + a.y * b.y + a.z * b.z + a.w * b.w;
}

// ---------------- K1: h partials: xc @ W1, 16 blocks x 32 rows ----------------
__global__ __launch_bounds__(256) void k1_hpart(
        const float* __restrict__ x, const float* __restrict__ read_prev,
        const float* __restrict__ reads_bias, const float* __restrict__ W1,
        float* __restrict__ part_h) {
    __shared__ float xc[512];
    int t = threadIdx.x;
    xc[t] = x[t];
    xc[256 + t] = read_prev[t] + reads_bias[t];
    __syncthreads();
    if (t < HID) {
        float acc = 0.f;
        int i0 = blockIdx.x * 32;
        #pragma unroll 8
        for (int r = 0; r < 32; ++r)
            acc += xc[i0 + r] * W1[(i0 + r) * HID + t];
        part_h[blockIdx.x * HID + t] = acc;
    }
}

// ---------------- K2: head GEMV partials: h @ {Wr, Ww}, 25 blocks x 8 rows ----
__global__ __launch_bounds__(256) void k2_heads(
        const float* __restrict__ part_h, const float* __restrict__ b1,
        const float* __restrict__ Wr, const float* __restrict__ Ww,
        float* __restrict__ part_or, float* __restrict__ part_ow) {
    __shared__ float h8[8];
    int t = threadIdx.x;
    if (t < 8) {
        int i = blockIdx.x * 8 + t;
        float v = b1[i];
        for (int b = 0; b < 16; ++b) v += part_h[b * HID + i];
        h8[t] = fmaxf(v, 0.f);
    }
    __syncthreads();
    float aor0 = 0.f, aor1 = 0.f, aow0 = 0.f, aow1 = 0.f, aow2 = 0.f, aow3 = 0.f;
    int i0 = blockIdx.x * 8;
    for (int r = 0; r < 8; ++r) {
        float hv = h8[r];
        const float* wr = Wr + (long long)(i0 + r) * ORD;
        const float* wwp = Ww + (long long)(i0 + r) * OWD;
        aor0 += hv * wr[t];
        if (t < 6) aor1 += hv * wr[256 + t];
        aow0 += hv * wwp[t];
        aow1 += hv * wwp[256 + t];
        aow2 += hv * wwp[512 + t];
        if (t < 6) aow3 += hv * wwp[768 + t];
    }
    part_or[blockIdx.x * ORD + t] = aor0;
    if (t < 6) part_or[blockIdx.x * ORD + 256 + t] = aor1;
    float* po = part_ow + blockIdx.x * OWD;
    po[t] = aow0;
    po[256 + t] = aow1;
    po[512 + t] = aow2;
    if (t < 6) po[768 + t] = aow3;
}

// ---------------- K3: finalize heads -> params in ws; zero accumulators ------
__global__ __launch_bounds__(256) void k3_params(
        const float* __restrict__ part_h, const float* __restrict__ b1,
        const float* __restrict__ part_or, const float* __restrict__ br,
        const float* __restrict__ part_ow, const float* __restrict__ bw,
        float* ws, float* __restrict__ read_out) {
    __shared__ float orh[ORD];
    __shared__ float owh[OWD];
    __shared__ float rbuf[8];
    int t = threadIdx.x;
    for (int j = t; j < ORD; j += 256) {
        float v = br[j];
        for (int b = 0; b < 25; ++b) v += part_or[b * ORD + j];
        orh[j] = v;
    }
    for (int j = t; j < OWD; j += 256) {
        float v = bw[j];
        for (int b = 0; b < 25; ++b) v += part_ow[b * OWD + j];
        owh[j] = v;
    }
    if (t < HID) {
        float v = b1[t];
        for (int b = 0; b < 16; ++b) v += part_h[b * HID + t];
        ws[WS_H + t] = fmaxf(v, 0.f);
    }
    read_out[t] = 0.f;                 // zero read accumulator (d_out region)
    if (t < 4) ws[WS_SC + 12 + t] = 0.f;  // zero sum_r, sum_w, sumwp_r, sumwp_w
    __syncthreads();

    float kr = tanhf(orh[t]);
    float kw = tanhf(owh[t]);
    float nr = kr * kr, nw = kw * kw;
    #pragma unroll
    for (int s = 32; s > 0; s >>= 1) {
        nr += __shfl_xor(nr, s, 64);
        nw += __shfl_xor(nw, s, 64);
    }
    int wid = t >> 6, lane = t & 63;
    if (lane == 0) { rbuf[wid] = nr; rbuf[4 + wid] = nw; }
    __syncthreads();
    float normr = sqrtf(rbuf[0] + rbuf[1] + rbuf[2] + rbuf[3]) + EPSV;
    float normw = sqrtf(rbuf[4] + rbuf[5] + rbuf[6] + rbuf[7]) + EPSV;
    ws[WS_KNR + t] = kr / normr;
    ws[WS_KNW + t] = kw / normw;
    ws[WS_E + t] = sigmoidf(owh[262 + t]);
    ws[WS_A + t] = tanhf(owh[518 + t]);
    if (t == 0) {
        ws[WS_SC + 0] = softplusf(orh[256]);
        ws[WS_SC + 1] = sigmoidf(orh[257]);
        float m3 = fmaxf(orh[258], fmaxf(orh[259], orh[260]));
        float e0 = expf(orh[258] - m3), e1 = expf(orh[259] - m3), e2 = expf(orh[260] - m3);
        float es = e0 + e1 + e2;
        ws[WS_SC + 2] = e0 / es; ws[WS_SC + 3] = e1 / es; ws[WS_SC + 4] = e2 / es;
        ws[WS_SC + 5] = 1.0f + softplusf(orh[261]);
        ws[WS_SC + 6] = softplusf(owh[256]);
        ws[WS_SC + 7] = sigmoidf(owh[257]);
        float m3w = fmaxf(owh[258], fmaxf(owh[259], owh[260]));
        float f0 = expf(owh[258] - m3w), f1 = expf(owh[259] - m3w), f2 = expf(owh[260] - m3w);
        float fs = f0 + f1 + f2;
        ws[WS_SC + 8] = f0 / fs; ws[WS_SC + 9] = f1 / fs; ws[WS_SC + 10] = f2 / fs;
        ws[WS_SC + 11] = 1.0f + softplusf(owh[261]);
    }
}

// ---------------- K4: M pass 1 — content scores -> u, sums -------------------
// 1024 blocks x 4 waves x 32 rows. 16 lanes per row, 4 rows in flight per wave:
// butterfly reduce only within 16-lane groups (12 shfl / 4 rows vs 18/row).
__global__ __launch_bounds__(256) void k4_scores(
        const float* __restrict__ M, float* ws,
        float* __restrict__ u_r, float* __restrict__ u_w) {
    __shared__ float sbuf[8];
    int t = threadIdx.x, lane = t & 63, wid = t >> 6;
    int lp = lane & 15;            // column-group within row
    int sub = lane >> 4;           // which of 4 concurrent rows
    f32x4 knr[4], knw[4];
    #pragma unroll
    for (int j = 0; j < 4; ++j) {
        knr[j] = *(const f32x4*)(ws + WS_KNR + j * 64 + lp * 4);
        knw[j] = *(const f32x4*)(ws + WS_KNW + j * 64 + lp * 4);
    }
    float beta_r = ws[WS_SC + 0], beta_w = ws[WS_SC + 6];
    int n0 = blockIdx.x * 128 + wid * 32;
    const float* mb = M + (long long)n0 * DM;
    float uval = 0.f;
    int my_i = (lane & 31) >> 2;   // iteration producing my target row
    int src = (lane & 3) * 16;     // lane holding that row's reduced value
    #pragma unroll
    for (int i = 0; i < 8; ++i) {
        const float* rp = mb + (i * 4 + sub) * DM + lp * 4;
        f32x4 a0 = *(const f32x4*)(rp);
        f32x4 a1 = *(const f32x4*)(rp + 64);
        f32x4 a2 = *(const f32x4*)(rp + 128);
        f32x4 a3 = *(const f32x4*)(rp + 192);
        float nn = dot4(a0, a0) + dot4(a1, a1) + dot4(a2, a2) + dot4(a3, a3);
        float dr = dot4(a0, knr[0]) + dot4(a1, knr[1]) + dot4(a2, knr[2]) + dot4(a3, knr[3]);
        float dw = dot4(a0, knw[0]) + dot4(a1, knw[1]) + dot4(a2, knw[2]) + dot4(a3, knw[3]);
        #pragma unroll
        for (int s = 1; s <= 8; s <<= 1) {
            nn += __shfl_xor(nn, s, 64);
            dr += __shfl_xor(dr, s, 64);
            dw += __shfl_xor(dw, s, 64);
        }
        float rn = 1.0f / (sqrtf(nn) + EPSV);
        // exp(beta*(cos-1)) == stabilized softmax numerator (cos <= 1)
        float ur = expf(beta_r * (dr * rn - 1.0f));
        float uw = expf(beta_w * (dw * rn - 1.0f));
        float vr = __shfl(ur, src, 64);
        float vw = __shfl(uw, src, 64);
        if (my_i == i) uval = (lane < 32) ? vr : vw;
    }
    // coalesced u store: lanes 0-31 -> u_r rows, 32-63 -> u_w rows
    if (lane < 32) u_r[n0 + lane] = uval;
    else           u_w[n0 + lane - 32] = uval;
    // wave sums: reduce uval within each 32-lane half
    float s5 = uval;
    #pragma unroll
    for (int s = 1; s <= 16; s <<= 1) s5 += __shfl_xor(s5, s, 64);
    if (lane == 0)  sbuf[wid] = s5;
    if (lane == 32) sbuf[4 + wid] = s5;
    __syncthreads();
    if (t == 0) {
        atomicAdd(&ws[WS_SC + 12], sbuf[0] + sbuf[1] + sbuf[2] + sbuf[3]);
        atomicAdd(&ws[WS_SC + 13], sbuf[4] + sbuf[5] + sbuf[6] + sbuf[7]);
    }
}

// ---------------- K5: gate + circular shift + pow + sum ----------------------
__global__ __launch_bounds__(256) void k5_shift(
        const float* __restrict__ u_r, const float* __restrict__ u_w,
        const float* __restrict__ read_w, const float* __restrict__ write_w,
        float* ws, float* __restrict__ wp_r, float* __restrict__ wp_w) {
    __shared__ float sbuf[8];
    int tid = blockIdx.x * 256 + threadIdx.x;
    float g_r = ws[WS_SC + 1], g_w = ws[WS_SC + 7];
    float omg_r = 1.f - g_r, omg_w = 1.f - g_w;
    float sr0 = ws[WS_SC + 2], sr1 = ws[WS_SC + 3], sr2 = ws[WS_SC + 4];
    float sw0 = ws[WS_SC + 8], sw1 = ws[WS_SC + 9], sw2 = ws[WS_SC + 10];
    float gam_r = ws[WS_SC + 5], gam_w = ws[WS_SC + 11];
    float isr = g_r / ws[WS_SC + 12];   // fold gate into softmax scale
    float isw = g_w / ws[WS_SC + 13];
    float lr = 0.f, lw = 0.f;
    for (int n = tid; n < NROWS; n += gridDim.x * 256) {
        int nm = (n == 0) ? NROWS - 1 : n - 1;
        int np = (n == NROWS - 1) ? 0 : n + 1;
        float wgm = u_r[nm] * isr + omg_r * read_w[nm];
        float wg0 = u_r[n]  * isr + omg_r * read_w[n];
        float wgp = u_r[np] * isr + omg_r * read_w[np];
        float wt = sr0 * wgp + sr1 * wg0 + sr2 * wgm;
        float wp = powf(wt, gam_r);
        wp_r[n] = wp; lr += wp;
        float vgm = u_w[nm] * isw + omg_w * write_w[nm];
        float vg0 = u_w[n]  * isw + omg_w * write_w[n];
        float vgp = u_w[np] * isw + omg_w * write_w[np];
        float vt = sw0 * vgp + sw1 * vg0 + sw2 * vgm;
        float vp = powf(vt, gam_w);
        wp_w[n] = vp; lw += vp;
    }
    #pragma unroll
    for (int s = 32; s > 0; s >>= 1) {
        lr += __shfl_xor(lr, s, 64);
        lw += __shfl_xor(lw, s, 64);
    }
    int wid = threadIdx.x >> 6, lane = threadIdx.x & 63;
    if (lane == 0) { sbuf[wid] = lr; sbuf[4 + wid] = lw; }
    __syncthreads();
    if (threadIdx.x == 0) {
        atomicAdd(&ws[WS_SC + 14], sbuf[0] + sbuf[1] + sbuf[2] + sbuf[3]);
        atomicAdd(&ws[WS_SC + 15], sbuf[4] + sbuf[5] + sbuf[6] + sbuf[7]);
    }
}

// ---------------- K6: M pass 2 — rw/ww finalize, M_new (nt), read partials ---
// 512 blocks x 4 waves x 64 rows (halved atomic contention on read[]).
__global__ __launch_bounds__(256) void k6_update(
        const float* __restrict__ M, float* ws, float* dout) {
    __shared__ float lds[4][256];
    int t = threadIdx.x, lane = t & 63, wid = t >> 6;
    const f32x4 e4 = *(const f32x4*)(ws + WS_E + lane * 4);
    const f32x4 a4 = *(const f32x4*)(ws + WS_A + lane * 4);
    float inv_r = 1.0f / (ws[WS_SC + 14] + EPSV);
    float inv_w = 1.0f / (ws[WS_SC + 15] + EPSV);
    float* rw = dout + RW_OFF;       // holds wp_r on entry
    float* wwb = dout + WW_OFF;      // holds wp_w on entry
    float* mn = dout + MNEW_OFF;
    int n0 = blockIdx.x * 256 + wid * 64;
    // wpva: rows 0..31 (r in lanes 0-31, w in 32-63); wpvb: rows 32..63
    float wpva = (lane < 32) ? rw[n0 + lane] : wwb[n0 + lane - 32];
    float wpvb = (lane < 32) ? rw[n0 + 32 + lane] : wwb[n0 + lane];
    const float* mb = M + (long long)n0 * DM + lane * 4;
    float* ob = mn + (long long)n0 * DM + lane * 4;
    f32x4 acc = {0.f, 0.f, 0.f, 0.f};
    #pragma unroll 8
    for (int r = 0; r < 64; ++r) {
        float rwv = ((r < 32) ? __shfl(wpva, r, 64) : __shfl(wpvb, r - 32, 64)) * inv_r;
        float wwv = ((r < 32) ? __shfl(wpva, 32 + r, 64) : __shfl(wpvb, r, 64)) * inv_w;
        const f32x4 m = *(const f32x4*)(mb + (long long)r * DM);
        f32x4 o;
        acc.x += rwv * m.x; acc.y += rwv * m.y;
        acc.z += rwv * m.z; acc.w += rwv * m.w;
        o.x = m.x * (1.0f - wwv * e4.x) + wwv * a4.x;
        o.y = m.y * (1.0f - wwv * e4.y) + wwv * a4.y;
        o.z = m.z * (1.0f - wwv * e4.z) + wwv * a4.z;
        o.w = m.w * (1.0f - wwv * e4.w) + wwv * a4.w;
        __builtin_nontemporal_store(o, (f32x4*)(ob + (long long)r * DM));
    }
    // write normalized weights back (coalesced, after all reads)
    if (lane < 32) { rw[n0 + lane] = wpva * inv_r; rw[n0 + 32 + lane] = wpvb * inv_r; }
    else           { wwb[n0 + lane - 32] = wpva * inv_w; wwb[n0 + lane] = wpvb * inv_w; }
    *(f32x4*)(&lds[wid][lane * 4]) = acc;
    __syncthreads();
    float s = lds[0][t] + lds[1][t] + lds[2][t] + lds[3][t];
    atomicAdd(&dout[READ_OFF + t], s);
}

// ---------------- K7: output MLP epilogue ------------------------------------
__global__ __launch_bounds__(256) void k7_out(
        const float* ws, const float* __restrict__ Wo1, const float* __restrict__ bo1,
        const float* __restrict__ Wo2, const float* __restrict__ bo2, float* dout) {
    __shared__ float c[456];
    __shared__ float h2[100];
    int t = threadIdx.x;
    if (t < HID) c[t] = ws[WS_H + t];
    c[200 + t] = dout[READ_OFF + t];
    __syncthreads();
    if (t < 100) {
        float acc = bo1[t];
        #pragma unroll 8
        for (int i = 0; i < 456; ++i) acc += c[i] * Wo1[i * 100 + t];
        h2[t] = fmaxf(acc, 0.f);
    }
    __syncthreads();
    if (t < 64) {
        float acc = bo2[t];
        #pragma unroll
        for (int i = 0; i < 100; ++i) acc += h2[i] * Wo2[i * 64 + t];
        dout[t] = acc;
    }
}

extern "C" void kernel_launch(void* const* d_in, const int* in_sizes, int n_in,
                              void* d_out, int out_size, void* d_ws, size_t ws_size,
                              hipStream_t stream) {
    const float* x          = (const float*)d_in[0];
    const float* M          = (const float*)d_in[1];
    const float* read_w     = (const float*)d_in[2];
    const float* write_w    = (const float*)d_in[3];
    const float* read_prev  = (const float*)d_in[4];
    const float* reads_bias = (const float*)d_in[5];
    const float* W1  = (const float*)d_in[6];
    const float* b1  = (const float*)d_in[7];
    const float* Wr  = (const float*)d_in[8];
    const float* br  = (const float*)d_in[9];
    const float* Ww  = (const float*)d_in[10];
    const float* bw  = (const float*)d_in[11];
    const float* Wo1 = (const float*)d_in[12];
    const float* bo1 = (const float*)d_in[13];
    const float* Wo2 = (const float*)d_in[14];
    const float* bo2 = (const float*)d_in[15];
    float* dout = (float*)d_out;
    float* ws   = (float*)d_ws;

    float* part_h  = dout + PART_H_OFF;
    float* part_or = dout + PART_OR_OFF;
    float* part_ow = dout + PART_OW_OFF;
    float* u_r = dout + U_R_OFF;
    float* u_w = dout + U_W_OFF;

    k1_hpart<<<16, 256, 0, stream>>>(x, read_prev, reads_bias, W1, part_h);
    k2_heads<<<25, 256, 0, stream>>>(part_h, b1, Wr, Ww, part_or, part_ow);
    k3_params<<<1, 256, 0, stream>>>(part_h, b1, part_or, br, part_ow, bw,
                                     ws, dout + READ_OFF);
    k4_scores<<<1024, 256, 0, stream>>>(M, ws, u_r, u_w);
    k5_shift<<<512, 256, 0, stream>>>(u_r, u_w, read_w, write_w, ws,
                                      dout + RW_OFF, dout + WW_OFF);
    k6_update<<<512, 256, 0, stream>>>(M, ws, dout);
    k7_out<<<1, 256, 0, stream>>>(ws, Wo1, bo1, Wo2, bo2, dout);
}